// Round 1
// baseline (416.013 us; speedup 1.0000x reference)
//
#include <hip/hip_runtime.h>
#include <cstdint>
#include <cstddef>

#pragma clang fp contract(off)

typedef unsigned long long u64;

#define NB 32
#define NA 9
#define NH 128
#define NW 128
#define HW (NH*NW)            // 16384
#define NANCH (NA*HW)         // 147456
#define PRE_N 6000
#define POST_N 300
#define CAND_CAP 8192
#define NMS_T 0.7f
#define GX_GATHER 24          // blocks per image in k_gather
#define NBOX 6144             // decoded boxes per image (PRE_N rounded up to chunk)
#define CH 512                // NMS chunk size

// Base anchor widths/heights (generate_anchors(16,[.5,1,2],[8,16,32])).
// All anchor centers are at (w*16+8, h*16+8) exactly (fp32-exact integers).
__constant__ float c_wa[9] = {184.f,368.f,736.f,128.f,256.f,512.f,88.f,176.f,352.f};
__constant__ float c_ha[9] = {96.f,192.f,384.f,128.f,256.f,512.f,176.f,352.f,704.f};

__device__ __forceinline__ float4 decode_clip(int a, int h, int w,
    float dx, float dy, float dlw, float dlh, float imh, float imw) {
  float wa = c_wa[a], ha = c_ha[a];
  float cx = (float)w * 16.0f + 8.0f;
  float cy = (float)h * 16.0f + 8.0f;
  float pcx = dx * wa + cx;
  float pcy = dy * ha + cy;
  float pw = expf(dlw) * wa;
  float ph = expf(dlh) * ha;
  float x1 = pcx - 0.5f * pw;
  float y1 = pcy - 0.5f * ph;
  float x2 = pcx + 0.5f * pw;
  float y2 = pcy + 0.5f * ph;
  float4 r;
  r.x = fminf(fmaxf(x1, 0.0f), imw - 1.0f);
  r.y = fminf(fmaxf(y1, 0.0f), imh - 1.0f);
  r.z = fminf(fmaxf(x2, 0.0f), imw - 1.0f);
  r.w = fminf(fmaxf(y2, 0.0f), imh - 1.0f);
  return r;
}

__device__ __forceinline__ unsigned score_key(float sc, float bw, float bh, float msz) {
  unsigned bits = __float_as_uint(sc);
  unsigned key = (bits & 0x80000000u) ? ~bits : (bits | 0x80000000u);
  if (!(bw >= msz && bh >= msz)) key = 0u;   // filtered == score NEG_INF
  return key;
}

// earlier/picked box (p,pa) vs candidate (v,ar):
// reference iou = inter / max(pa + ar - inter, 1e-6)
__device__ __forceinline__ bool sup_test4(float4 v, float ar, float4 p, float pa) {
  float xx1 = fmaxf(p.x, v.x), yy1 = fmaxf(p.y, v.y);
  float xx2 = fminf(p.z, v.z), yy2 = fminf(p.w, v.w);
  float iw = fmaxf(xx2 - xx1 + 1.0f, 0.0f);
  float ih = fmaxf(yy2 - yy1 + 1.0f, 0.0f);
  float inter = iw * ih;
  float iou = inter / fmaxf(pa + ar - inter, 1e-6f);
  return iou > NMS_T;
}

// ---- inline radix-select helpers (256-thread blocks) -----------------------
__device__ void find_B(const unsigned* __restrict__ hb, unsigned* part,
                       unsigned* outB, unsigned* outCum) {
  int tid = threadIdx.x;
  unsigned s = 0;
  for (int i = 0; i < 16; ++i) s += hb[tid*16 + i];
  part[tid] = s;
  __syncthreads();
  for (int off = 1; off < 256; off <<= 1) {
    unsigned v = (tid + off < 256) ? part[tid + off] : 0u;
    __syncthreads();
    part[tid] += v;
    __syncthreads();
  }
  unsigned St = part[tid];
  unsigned Sn = (tid < 255) ? part[tid + 1] : 0u;
  if (St >= (unsigned)PRE_N && Sn < (unsigned)PRE_N) {
    unsigned cum = Sn, B = 0, cumAbove = Sn;
    for (int i = 15; i >= 0; --i) {
      unsigned v = hb[tid*16 + i];
      if (cum + v >= (unsigned)PRE_N) { B = (unsigned)(tid*16 + i); cumAbove = cum; break; }
      cum += v;
    }
    *outB = B; *outCum = cumAbove;
  }
  __syncthreads();
}

__device__ void find_thr(const unsigned* __restrict__ hb2, unsigned B, unsigned cum0,
                         unsigned* part, unsigned* outThr) {
  int tid = threadIdx.x;
  unsigned s = 0;
  for (int i = 0; i < 16; ++i) s += hb2[tid*16 + i];
  part[tid] = s;
  __syncthreads();
  for (int off = 1; off < 256; off <<= 1) {
    unsigned v = (tid + off < 256) ? part[tid + off] : 0u;
    __syncthreads();
    part[tid] += v;
    __syncthreads();
  }
  unsigned St = cum0 + part[tid];
  unsigned Sn = cum0 + ((tid < 255) ? part[tid + 1] : 0u);
  if (St >= (unsigned)PRE_N && Sn < (unsigned)PRE_N) {
    unsigned cum = Sn, t = 1u;
    for (int i = 15; i >= 0; --i) {
      unsigned v = hb2[tid*16 + i];
      if (cum + v >= (unsigned)PRE_N) {
        t = (B << 20) | ((unsigned)(tid*16 + i) << 8);
        break;
      }
      cum += v;
    }
    if (t == 0u) t = 1u;
    *outThr = t;
  }
  __syncthreads();
}

// K1: decode+filter -> order-preserving uint key per anchor, fused coarse
// histogram (key>>20, 4096 bins) aggregated in LDS, flushed per block.
// grid (16, NB): 9216 keys per block -> one dense flush per block.
__global__ __launch_bounds__(256) void k_keys(const float* __restrict__ cls,
    const float* __restrict__ dl, const float* __restrict__ info,
    unsigned* __restrict__ keys, unsigned* __restrict__ hist) {
  __shared__ unsigned hsh[4096];
  int tid = threadIdx.x;
  for (int i = tid; i < 4096; i += 256) hsh[i] = 0;
  int t = blockIdx.x * 256 + tid;            // 0..4095
  int b = blockIdx.y;
  int hw0 = t * 4;                           // 4 consecutive hw, same row
  int h = hw0 >> 7;
  const float* dlb  = dl  + (size_t)b * (4*NA*HW);
  const float* clsb = cls + (size_t)b * (2*NA*HW);
  float imh = info[b*3+0], imw = info[b*3+1];
  float msz = 16.0f * info[b*3+2];
  unsigned* kb = keys + (size_t)b * NANCH;
  __syncthreads();
  #pragma unroll
  for (int a = 0; a < 9; ++a) {
    float4 dx4 = *(const float4*)&dlb[(a*4+0)*HW + hw0];
    float4 dy4 = *(const float4*)&dlb[(a*4+1)*HW + hw0];
    float4 dw4 = *(const float4*)&dlb[(a*4+2)*HW + hw0];
    float4 dh4 = *(const float4*)&dlb[(a*4+3)*HW + hw0];
    float4 sc4 = *(const float4*)&clsb[(NA+a)*HW + hw0];
    uint4 out;
    {
      float4 bx = decode_clip(a, h, (hw0+0)&127, dx4.x, dy4.x, dw4.x, dh4.x, imh, imw);
      out.x = score_key(sc4.x, bx.z-bx.x+1.0f, bx.w-bx.y+1.0f, msz);
    }
    {
      float4 bx = decode_clip(a, h, (hw0+1)&127, dx4.y, dy4.y, dw4.y, dh4.y, imh, imw);
      out.y = score_key(sc4.y, bx.z-bx.x+1.0f, bx.w-bx.y+1.0f, msz);
    }
    {
      float4 bx = decode_clip(a, h, (hw0+2)&127, dx4.z, dy4.z, dw4.z, dh4.z, imh, imw);
      out.z = score_key(sc4.z, bx.z-bx.x+1.0f, bx.w-bx.y+1.0f, msz);
    }
    {
      float4 bx = decode_clip(a, h, (hw0+3)&127, dx4.w, dy4.w, dw4.w, dh4.w, imh, imw);
      out.w = score_key(sc4.w, bx.z-bx.x+1.0f, bx.w-bx.y+1.0f, msz);
    }
    *(uint4*)&kb[a*HW + hw0] = out;
    atomicAdd(&hsh[out.x >> 20], 1u);
    atomicAdd(&hsh[out.y >> 20], 1u);
    atomicAdd(&hsh[out.z >> 20], 1u);
    atomicAdd(&hsh[out.w >> 20], 1u);
  }
  __syncthreads();
  unsigned* gb = hist + ((size_t)b << 12);
  for (int i = tid; i < 4096; i += 256) {
    unsigned v = hsh[i];
    if (v) atomicAdd(&gb[i], v);
  }
}

// K2: refine histogram — bits[19:8] of keys whose top-12 == B (B inline from h1).
__global__ __launch_bounds__(256) void k_hist2(const unsigned* __restrict__ keys,
    const unsigned* __restrict__ hist1, unsigned* __restrict__ hist2) {
  __shared__ unsigned h[4096];
  __shared__ unsigned part[256];
  __shared__ unsigned sB, sCum;
  int b = blockIdx.y, tid = threadIdx.x;
  for (int i = tid; i < 4096; i += 256) h[i] = 0;
  __syncthreads();
  find_B(hist1 + ((size_t)b << 12), part, &sB, &sCum);
  unsigned B = sB;
  const unsigned* kb = keys + (size_t)b * NANCH;
  for (int i = blockIdx.x * 256 + tid; i < NANCH; i += gridDim.x * 256) {
    unsigned k = kb[i];
    if ((k >> 20) == B) atomicAdd(&h[(k >> 8) & 4095u], 1u);
  }
  __syncthreads();
  unsigned* gb = hist2 + ((size_t)b << 12);
  for (int i = tid; i < 4096; i += 256) { unsigned v = h[i]; if (v) atomicAdd(&gb[i], v); }
}

// K3: gather (key, ~origidx) for key >= thr (thr inline from h1+h2).
__global__ __launch_bounds__(256) void k_gather(const unsigned* __restrict__ keys,
    const unsigned* __restrict__ hist1, const unsigned* __restrict__ hist2,
    unsigned* __restrict__ cnt, u64* __restrict__ cand) {
  int b = blockIdx.y, tid = threadIdx.x;
  int lane = tid & 63, wv = tid >> 6;
  __shared__ unsigned part[256];
  __shared__ unsigned sB, sCum, sThr;
  __shared__ unsigned wcnt[4], woff[4], blkbase;
  if (tid == 0) sThr = 1u;
  __syncthreads();
  find_B(hist1 + ((size_t)b << 12), part, &sB, &sCum);
  find_thr(hist2 + ((size_t)b << 12), sB, sCum, part, &sThr);
  unsigned t_ = sThr;
  const unsigned* kb = keys + (size_t)b * NANCH;
  u64* cb = cand + (size_t)b * CAND_CAP;
  unsigned* cp = cnt + (size_t)b * 64;
  const int PER_BLK = NANCH / GX_GATHER;      // 6144
  int base0 = blockIdx.x * PER_BLK;
  for (int it = 0; it < PER_BLK / 256; ++it) {
    int j = base0 + it * 256 + tid;
    unsigned key = kb[j];
    bool pass = key >= t_;
    u64 mask = __ballot(pass);
    if (lane == 0) wcnt[wv] = (unsigned)__popcll(mask);
    __syncthreads();
    if (tid == 0) {
      unsigned s0 = 0;
      for (int w = 0; w < 4; ++w) { woff[w] = s0; s0 += wcnt[w]; }
      blkbase = s0 ? atomicAdd(cp, s0) : 0u;
    }
    __syncthreads();
    if (pass) {
      unsigned pos = blkbase + woff[wv] + (unsigned)__popcll(mask & ((1ull << lane) - 1ull));
      if (pos < CAND_CAP) {
        int a = j >> 14, hw = j & (HW - 1);
        unsigned oi = (unsigned)(hw * 9 + a);
        cb[pos] = ((u64)key << 32) | (unsigned)(~oi);
      }
    }
    __syncthreads();
  }
}

// K4: local sort of 2048-chunks (masks unwritten slots to 0 via cnt).
// 128 blocks. Chunk c: desc iff c even.
__global__ __launch_bounds__(256) void k_sortA(u64* __restrict__ cand,
                                               const unsigned* __restrict__ cnt) {
  __shared__ u64 sm[2048];   // 16 KiB
  int blk = blockIdx.x;
  int b = blk >> 2, c = blk & 3;
  unsigned effcnt = cnt[b * 64];
  if (effcnt > CAND_CAP) effcnt = CAND_CAP;
  u64* cb = cand + (size_t)b * CAND_CAP + (size_t)c * 2048;
  int base = c * 2048;
  int tid = threadIdx.x;
  for (int t = tid; t < 2048; t += 256)
    sm[t] = ((unsigned)(base + t) < effcnt) ? cb[t] : 0ull;
  bool blkdesc = (c & 1) == 0;
  for (int k = 2; k <= 2048; k <<= 1) {
    for (int j = k >> 1; j > 0; j >>= 1) {
      __syncthreads();
      for (int t = tid; t < 2048; t += 256) {
        int p = t ^ j;
        if (p > t) {
          bool up = (k == 2048) ? blkdesc : ((t & k) == 0);
          u64 x = sm[t], y = sm[p];
          if (up ? (x < y) : (x > y)) { sm[t] = y; sm[p] = x; }
        }
      }
    }
  }
  __syncthreads();
  for (int t = tid; t < 2048; t += 256) cb[t] = sm[t];
}

// K5: bitonic merge of 4096-blocks; block m desc iff m even. 64 blocks.
__global__ __launch_bounds__(512) void k_merge4096(u64* __restrict__ cand) {
  __shared__ u64 sm[4096];   // 32 KiB
  int blk = blockIdx.x;
  int b = blk >> 1, m = blk & 1;
  u64* cb = cand + (size_t)b * CAND_CAP + (size_t)m * 4096;
  int tid = threadIdx.x;
  for (int t = tid; t < 4096; t += 512) sm[t] = cb[t];
  bool desc = (m & 1) == 0;
  for (int j = 2048; j > 0; j >>= 1) {
    __syncthreads();
    for (int t = tid; t < 4096; t += 512) {
      int p = t ^ j;
      if (p > t) {
        u64 x = sm[t], y = sm[p];
        if (desc ? (x < y) : (x > y)) { sm[t] = y; sm[p] = x; }
      }
    }
  }
  __syncthreads();
  for (int t = tid; t < 4096; t += 512) cb[t] = sm[t];
}

// K6: final merge (k=8192 desc, 13 phases, in LDS) + PARALLEL box decode.
// Writes decoded float4 boxes (top NBOX per image) to global; invalid slots
// get (0,0,-1,-1) so width = z-x+1 = 0 marks them.
__global__ __launch_bounds__(1024) void k_mergedec(const u64* __restrict__ cand,
    const float* __restrict__ dl, const float* __restrict__ info,
    float4* __restrict__ boxes) {
  __shared__ u64 sm[CAND_CAP];   // 64 KiB
  int b = blockIdx.x, tid = threadIdx.x;
  const u64* cb = cand + (size_t)b * CAND_CAP;
  for (int t = tid; t < CAND_CAP; t += 1024) sm[t] = cb[t];
  for (int j = CAND_CAP >> 1; j > 0; j >>= 1) {
    __syncthreads();
    for (int t = tid; t < CAND_CAP; t += 1024) {
      int p = t ^ j;
      if (p > t) {
        u64 x = sm[t], y = sm[p];
        if (x < y) { sm[t] = y; sm[p] = x; }
      }
    }
  }
  __syncthreads();
  const float* dlb = dl + (size_t)b * (4*NA*HW);
  float imh = info[b*3+0], imw = info[b*3+1];
  float4* bxout = boxes + (size_t)b * NBOX;
  for (int t = tid; t < NBOX; t += 1024) {
    u64 ck = (t < PRE_N) ? sm[t] : 0ull;
    float4 v = make_float4(0.f, 0.f, -1.f, -1.f);
    if ((unsigned)(ck >> 32) != 0u) {
      int idx = (int)(~(unsigned)(ck & 0xFFFFFFFFull));
      int a = idx % 9, hw = idx / 9;
      v = decode_clip(a, hw >> 7, hw & 127,
                      dlb[(a*4+0)*HW + hw], dlb[(a*4+1)*HW + hw],
                      dlb[(a*4+2)*HW + hw], dlb[(a*4+3)*HW + hw], imh, imw);
    }
    bxout[t] = v;
  }
}

// K7: greedy NMS over precomputed boxes, all LDS-resident.
// Chunk = 512 candidates (12 chunks, 6 barriers each = 72 barriers total).
__global__ __launch_bounds__(1024) void k_nms(const float4* __restrict__ boxes,
    float* __restrict__ out) {
  __shared__ float4 bx[NBOX];        // 96 KiB
  __shared__ float4 kbox[POST_N];
  __shared__ float  karea[POST_N];
  __shared__ float  carea[CH];
  __shared__ unsigned supf[CH];
  __shared__ u64 sup[CH][8];         // 32 KiB
  __shared__ u64 aliveM[8];
  __shared__ u64 kgW[8];
  __shared__ int s_nk;
  int b = blockIdx.x, tid = threadIdx.x;
  int lane = tid & 63, wv = tid >> 6;      // wv 0..15
  int c = tid & (CH - 1);                  // candidate within chunk
  int seg = tid >> 9;                      // 0/1 depth split
  int cg = c >> 6;                         // candidate's 64-group 0..7
  if (tid == 0) s_nk = 0;
  const float4* gb = boxes + (size_t)b * NBOX;
  for (int t = tid; t < NBOX; t += 1024) bx[t] = gb[t];
  float* ob = out + (size_t)b * (POST_N * 5);
  volatile unsigned* svf = supf;
  __syncthreads();

  for (int base = 0; base < NBOX; base += CH) {
    if (tid < CH) {
      float4 v = bx[base + tid];
      float w = v.z - v.x + 1.0f, h = v.w - v.y + 1.0f;
      carea[tid] = w * h;
      supf[tid] = (w > 0.0f) ? 0u : 1u;    // w==0 marks invalid slot
    }
    __syncthreads();                                          // B1
    int nk0 = s_nk;

    // pre-filter vs kept list: 2-way depth split, cross-half poll
    if (supf[c] == 0u) {
      float4 v = bx[base + c]; float ar = carea[c];
      for (int k = seg; k < nk0; k += 2) {
        if (svf[c]) break;
        if (sup_test4(v, ar, kbox[k], karea[k])) { atomicOr(&supf[c], 1u); break; }
      }
    }
    __syncthreads();                                          // B2

    if (tid < CH) {
      u64 am = __ballot(supf[tid] == 0u);
      if (lane == 0) aliveM[wv] = am;
    }
    __syncthreads();                                          // B3
    u64 anyAlive = aliveM[0]|aliveM[1]|aliveM[2]|aliveM[3]|
                   aliveM[4]|aliveM[5]|aliveM[6]|aliveM[7];
    if (anyAlive == 0ull) continue;

    // intra-chunk suppression matrix: thread (c,seg) covers groups seg*4..seg*4+3
    if (supf[c] == 0u) {
      float4 v = bx[base + c]; float ar = carea[c];
      #pragma unroll
      for (int gg = 0; gg < 4; ++gg) {
        int g = seg * 4 + gg;
        if (g <= cg) {
          u64 m = aliveM[g];
          if (g == cg) m &= (1ull << (c & 63)) - 1ull;
          u64 r = 0;
          while (m) {
            int j = __builtin_ctzll(m);
            m &= m - 1;
            int col = g * 64 + j;
            if (sup_test4(v, ar, bx[base + col], carea[col])) r |= 1ull << j;
          }
          sup[c][g] = r;
        }
      }
    }
    __syncthreads();                                          // B4

    // greedy resolve by wave 0, 8 sequential group stages
    if (wv == 0) {
      u64 kw[8];
      #pragma unroll
      for (int s = 0; s < 8; ++s) {
        int cc = s * 64 + lane;
        bool a = (aliveM[s] >> lane) & 1;
        #pragma unroll
        for (int g = 0; g < 8; ++g) {
          if (g < s && a) a = (sup[cc][g] & kw[g]) == 0ull;
        }
        u64 r = a ? sup[cc][s] : 0ull;
        u64 cm = __ballot(a), kg = 0;
        while (cm) {
          int j = __builtin_ctzll(cm);
          kg |= 1ull << j;
          u64 rem = __ballot((r >> j) & 1);
          cm &= ~(rem | (1ull << j));
        }
        kw[s] = kg;
      }
      if (lane == 0) {
        #pragma unroll
        for (int s = 0; s < 8; ++s) kgW[s] = kw[s];
      }
    }
    __syncthreads();                                          // B5

    // append kept boxes + update s_nk
    if (tid < CH) {
      u64 kgw = kgW[wv];
      bool kept = (kgw >> lane) & 1;
      int pre = 0;
      for (int g = 0; g < wv; ++g) pre += (int)__popcll(kgW[g]);
      pre += (int)__popcll(kgw & ((1ull << lane) - 1ull));
      int rank = nk0 + pre;
      if (kept && rank < POST_N) {
        float4 v = bx[base + tid];
        kbox[rank] = v; karea[rank] = carea[tid];
        ob[rank*5+0] = (float)b;
        ob[rank*5+1] = v.x; ob[rank*5+2] = v.y; ob[rank*5+3] = v.z; ob[rank*5+4] = v.w;
      }
    }
    if (tid == 0) {
      int tot = 0;
      #pragma unroll
      for (int s = 0; s < 8; ++s) tot += (int)__popcll(kgW[s]);
      int nn = nk0 + tot;
      s_nk = nn < POST_N ? nn : POST_N;
    }
    __syncthreads();                                          // B6
    if (s_nk >= POST_N) break;
  }
  __syncthreads();
  int nk = s_nk;
  for (int r = nk + tid; r < POST_N; r += 1024) {
    ob[r*5+0] = (float)b;
    ob[r*5+1] = 0.f; ob[r*5+2] = 0.f; ob[r*5+3] = 0.f; ob[r*5+4] = 0.f;
  }
}

extern "C" void kernel_launch(void* const* d_in, const int* in_sizes, int n_in,
                              void* d_out, int out_size, void* d_ws, size_t ws_size,
                              hipStream_t stream) {
  const float* cls  = (const float*)d_in[0];   // (32, 18, 128, 128)
  const float* dl   = (const float*)d_in[1];   // (32, 36, 128, 128)
  const float* info = (const float*)d_in[2];   // (32, 3)
  float* out = (float*)d_out;                  // (32, 300, 5)
  char* ws = (char*)d_ws;

  // workspace layout (bytes)
  const size_t OFF_KEYS = 0;                        // 32*147456*4 = 18,874,368
  const size_t OFF_H1   = 18874368;                 // 32*4096*4   =    524,288
  const size_t OFF_H2   = 19398656;                 // 32*4096*4   =    524,288
  const size_t OFF_CNT  = 19922944;                 // 32*64*4     =      8,192
  const size_t OFF_CAND = 19931136;                 // 32*8192*8   =  2,097,152
  const size_t WS_NEED  = 22028288;
  if (ws_size < WS_NEED) return;

  unsigned* keys  = (unsigned*)(ws + OFF_KEYS);
  unsigned* h1    = (unsigned*)(ws + OFF_H1);
  unsigned* h2    = (unsigned*)(ws + OFF_H2);
  unsigned* cnt   = (unsigned*)(ws + OFF_CNT);
  u64* cand = (u64*)(ws + OFF_CAND);
  // boxes buffer aliases the keys region (keys dead after k_gather):
  // 32*6144*16 = 3,145,728 bytes <= 18,874,368
  float4* boxes = (float4*)(ws + OFF_KEYS);

  // zero h1 + h2 + cnt only (cand masked by cnt in k_sortA)
  hipMemsetAsync(ws + OFF_H1, 0, OFF_CAND - OFF_H1, stream);

  dim3 g1(HW / 1024, NB);                 // (16, 32)
  k_keys<<<g1, 256, 0, stream>>>(cls, dl, info, keys, h1);
  dim3 gh(8, NB);
  k_hist2<<<gh, 256, 0, stream>>>(keys, h1, h2);
  dim3 gg(GX_GATHER, NB);
  k_gather<<<gg, 256, 0, stream>>>(keys, h1, h2, cnt, cand);
  k_sortA<<<NB * 4, 256, 0, stream>>>(cand, cnt);
  k_merge4096<<<NB * 2, 512, 0, stream>>>(cand);
  k_mergedec<<<NB, 1024, 0, stream>>>(cand, dl, info, boxes);
  k_nms<<<NB, 1024, 0, stream>>>(boxes, out);
}

// Round 3
// 411.000 us; speedup vs baseline: 1.0122x; 1.0122x over previous
//
#include <hip/hip_runtime.h>
#include <cstdint>
#include <cstddef>

#pragma clang fp contract(off)

typedef unsigned long long u64;

#define NB 32
#define NA 9
#define NH 128
#define NW 128
#define HW (NH*NW)            // 16384
#define NANCH (NA*HW)         // 147456
#define PRE_N 6000
#define POST_N 300
#define CAND_CAP 8192
#define NMS_T 0.7f
#define GX_GATHER 24          // blocks per image in k_gather
#define NBOX 6144             // decoded boxes per image (PRE_N rounded up to chunk)
#define CH 512                // NMS chunk size

// Base anchor widths/heights (generate_anchors(16,[.5,1,2],[8,16,32])).
// All anchor centers are at (w*16+8, h*16+8) exactly (fp32-exact integers).
__constant__ float c_wa[9] = {184.f,368.f,736.f,128.f,256.f,512.f,88.f,176.f,352.f};
__constant__ float c_ha[9] = {96.f,192.f,384.f,128.f,256.f,512.f,176.f,352.f,704.f};

__device__ __forceinline__ float4 decode_clip(int a, int h, int w,
    float dx, float dy, float dlw, float dlh, float imh, float imw) {
  float wa = c_wa[a], ha = c_ha[a];
  float cx = (float)w * 16.0f + 8.0f;
  float cy = (float)h * 16.0f + 8.0f;
  float pcx = dx * wa + cx;
  float pcy = dy * ha + cy;
  float pw = expf(dlw) * wa;
  float ph = expf(dlh) * ha;
  float x1 = pcx - 0.5f * pw;
  float y1 = pcy - 0.5f * ph;
  float x2 = pcx + 0.5f * pw;
  float y2 = pcy + 0.5f * ph;
  float4 r;
  r.x = fminf(fmaxf(x1, 0.0f), imw - 1.0f);
  r.y = fminf(fmaxf(y1, 0.0f), imh - 1.0f);
  r.z = fminf(fmaxf(x2, 0.0f), imw - 1.0f);
  r.w = fminf(fmaxf(y2, 0.0f), imh - 1.0f);
  return r;
}

__device__ __forceinline__ unsigned score_key(float sc, float bw, float bh, float msz) {
  unsigned bits = __float_as_uint(sc);
  unsigned key = (bits & 0x80000000u) ? ~bits : (bits | 0x80000000u);
  if (!(bw >= msz && bh >= msz)) key = 0u;   // filtered == score NEG_INF
  return key;
}

// earlier/picked box (p,pa) vs candidate (v,ar):
// reference iou = inter / max(pa + ar - inter, 1e-6)
__device__ __forceinline__ bool sup_test4(float4 v, float ar, float4 p, float pa) {
  float xx1 = fmaxf(p.x, v.x), yy1 = fmaxf(p.y, v.y);
  float xx2 = fminf(p.z, v.z), yy2 = fminf(p.w, v.w);
  float iw = fmaxf(xx2 - xx1 + 1.0f, 0.0f);
  float ih = fmaxf(yy2 - yy1 + 1.0f, 0.0f);
  float inter = iw * ih;
  float iou = inter / fmaxf(pa + ar - inter, 1e-6f);
  return iou > NMS_T;
}

// ---- inline radix-select helpers (256-thread blocks) -----------------------
__device__ void find_B(const unsigned* __restrict__ hb, unsigned* part,
                       unsigned* outB, unsigned* outCum) {
  int tid = threadIdx.x;
  unsigned s = 0;
  for (int i = 0; i < 16; ++i) s += hb[tid*16 + i];
  part[tid] = s;
  __syncthreads();
  for (int off = 1; off < 256; off <<= 1) {
    unsigned v = (tid + off < 256) ? part[tid + off] : 0u;
    __syncthreads();
    part[tid] += v;
    __syncthreads();
  }
  unsigned St = part[tid];
  unsigned Sn = (tid < 255) ? part[tid + 1] : 0u;
  if (St >= (unsigned)PRE_N && Sn < (unsigned)PRE_N) {
    unsigned cum = Sn, B = 0, cumAbove = Sn;
    for (int i = 15; i >= 0; --i) {
      unsigned v = hb[tid*16 + i];
      if (cum + v >= (unsigned)PRE_N) { B = (unsigned)(tid*16 + i); cumAbove = cum; break; }
      cum += v;
    }
    *outB = B; *outCum = cumAbove;
  }
  __syncthreads();
}

__device__ void find_thr(const unsigned* __restrict__ hb2, unsigned B, unsigned cum0,
                         unsigned* part, unsigned* outThr) {
  int tid = threadIdx.x;
  unsigned s = 0;
  for (int i = 0; i < 16; ++i) s += hb2[tid*16 + i];
  part[tid] = s;
  __syncthreads();
  for (int off = 1; off < 256; off <<= 1) {
    unsigned v = (tid + off < 256) ? part[tid + off] : 0u;
    __syncthreads();
    part[tid] += v;
    __syncthreads();
  }
  unsigned St = cum0 + part[tid];
  unsigned Sn = cum0 + ((tid < 255) ? part[tid + 1] : 0u);
  if (St >= (unsigned)PRE_N && Sn < (unsigned)PRE_N) {
    unsigned cum = Sn, t = 1u;
    for (int i = 15; i >= 0; --i) {
      unsigned v = hb2[tid*16 + i];
      if (cum + v >= (unsigned)PRE_N) {
        t = (B << 20) | ((unsigned)(tid*16 + i) << 8);
        break;
      }
      cum += v;
    }
    if (t == 0u) t = 1u;
    *outThr = t;
  }
  __syncthreads();
}

// K1: decode+filter -> order-preserving uint key per anchor, fused coarse
// histogram (key>>20, 4096 bins) aggregated in LDS, flushed per block.
// grid (16, NB): 9216 keys per block -> one dense flush per block.
__global__ __launch_bounds__(256) void k_keys(const float* __restrict__ cls,
    const float* __restrict__ dl, const float* __restrict__ info,
    unsigned* __restrict__ keys, unsigned* __restrict__ hist) {
  __shared__ unsigned hsh[4096];
  int tid = threadIdx.x;
  for (int i = tid; i < 4096; i += 256) hsh[i] = 0;
  int t = blockIdx.x * 256 + tid;            // 0..4095
  int b = blockIdx.y;
  int hw0 = t * 4;                           // 4 consecutive hw, same row
  int h = hw0 >> 7;
  const float* dlb  = dl  + (size_t)b * (4*NA*HW);
  const float* clsb = cls + (size_t)b * (2*NA*HW);
  float imh = info[b*3+0], imw = info[b*3+1];
  float msz = 16.0f * info[b*3+2];
  unsigned* kb = keys + (size_t)b * NANCH;
  __syncthreads();
  #pragma unroll
  for (int a = 0; a < 9; ++a) {
    float4 dx4 = *(const float4*)&dlb[(a*4+0)*HW + hw0];
    float4 dy4 = *(const float4*)&dlb[(a*4+1)*HW + hw0];
    float4 dw4 = *(const float4*)&dlb[(a*4+2)*HW + hw0];
    float4 dh4 = *(const float4*)&dlb[(a*4+3)*HW + hw0];
    float4 sc4 = *(const float4*)&clsb[(NA+a)*HW + hw0];
    uint4 out;
    {
      float4 bx = decode_clip(a, h, (hw0+0)&127, dx4.x, dy4.x, dw4.x, dh4.x, imh, imw);
      out.x = score_key(sc4.x, bx.z-bx.x+1.0f, bx.w-bx.y+1.0f, msz);
    }
    {
      float4 bx = decode_clip(a, h, (hw0+1)&127, dx4.y, dy4.y, dw4.y, dh4.y, imh, imw);
      out.y = score_key(sc4.y, bx.z-bx.x+1.0f, bx.w-bx.y+1.0f, msz);
    }
    {
      float4 bx = decode_clip(a, h, (hw0+2)&127, dx4.z, dy4.z, dw4.z, dh4.z, imh, imw);
      out.z = score_key(sc4.z, bx.z-bx.x+1.0f, bx.w-bx.y+1.0f, msz);
    }
    {
      float4 bx = decode_clip(a, h, (hw0+3)&127, dx4.w, dy4.w, dw4.w, dh4.w, imh, imw);
      out.w = score_key(sc4.w, bx.z-bx.x+1.0f, bx.w-bx.y+1.0f, msz);
    }
    *(uint4*)&kb[a*HW + hw0] = out;
    atomicAdd(&hsh[out.x >> 20], 1u);
    atomicAdd(&hsh[out.y >> 20], 1u);
    atomicAdd(&hsh[out.z >> 20], 1u);
    atomicAdd(&hsh[out.w >> 20], 1u);
  }
  __syncthreads();
  unsigned* gb = hist + ((size_t)b << 12);
  for (int i = tid; i < 4096; i += 256) {
    unsigned v = hsh[i];
    if (v) atomicAdd(&gb[i], v);
  }
}

// K2: refine histogram — bits[19:8] of keys whose top-12 == B (B inline from h1).
__global__ __launch_bounds__(256) void k_hist2(const unsigned* __restrict__ keys,
    const unsigned* __restrict__ hist1, unsigned* __restrict__ hist2) {
  __shared__ unsigned h[4096];
  __shared__ unsigned part[256];
  __shared__ unsigned sB, sCum;
  int b = blockIdx.y, tid = threadIdx.x;
  for (int i = tid; i < 4096; i += 256) h[i] = 0;
  __syncthreads();
  find_B(hist1 + ((size_t)b << 12), part, &sB, &sCum);
  unsigned B = sB;
  const unsigned* kb = keys + (size_t)b * NANCH;
  for (int i = blockIdx.x * 256 + tid; i < NANCH; i += gridDim.x * 256) {
    unsigned k = kb[i];
    if ((k >> 20) == B) atomicAdd(&h[(k >> 8) & 4095u], 1u);
  }
  __syncthreads();
  unsigned* gb = hist2 + ((size_t)b << 12);
  for (int i = tid; i < 4096; i += 256) { unsigned v = h[i]; if (v) atomicAdd(&gb[i], v); }
}

// K3: gather (key, ~origidx) for key >= thr (thr inline from h1+h2).
__global__ __launch_bounds__(256) void k_gather(const unsigned* __restrict__ keys,
    const unsigned* __restrict__ hist1, const unsigned* __restrict__ hist2,
    unsigned* __restrict__ cnt, u64* __restrict__ cand) {
  int b = blockIdx.y, tid = threadIdx.x;
  int lane = tid & 63, wv = tid >> 6;
  __shared__ unsigned part[256];
  __shared__ unsigned sB, sCum, sThr;
  __shared__ unsigned wcnt[4], woff[4], blkbase;
  if (tid == 0) sThr = 1u;
  __syncthreads();
  find_B(hist1 + ((size_t)b << 12), part, &sB, &sCum);
  find_thr(hist2 + ((size_t)b << 12), sB, sCum, part, &sThr);
  unsigned t_ = sThr;
  const unsigned* kb = keys + (size_t)b * NANCH;
  u64* cb = cand + (size_t)b * CAND_CAP;
  unsigned* cp = cnt + (size_t)b * 64;
  const int PER_BLK = NANCH / GX_GATHER;      // 6144
  int base0 = blockIdx.x * PER_BLK;
  for (int it = 0; it < PER_BLK / 256; ++it) {
    int j = base0 + it * 256 + tid;
    unsigned key = kb[j];
    bool pass = key >= t_;
    u64 mask = __ballot(pass);
    if (lane == 0) wcnt[wv] = (unsigned)__popcll(mask);
    __syncthreads();
    if (tid == 0) {
      unsigned s0 = 0;
      for (int w = 0; w < 4; ++w) { woff[w] = s0; s0 += wcnt[w]; }
      blkbase = s0 ? atomicAdd(cp, s0) : 0u;
    }
    __syncthreads();
    if (pass) {
      unsigned pos = blkbase + woff[wv] + (unsigned)__popcll(mask & ((1ull << lane) - 1ull));
      if (pos < CAND_CAP) {
        int a = j >> 14, hw = j & (HW - 1);
        unsigned oi = (unsigned)(hw * 9 + a);
        cb[pos] = ((u64)key << 32) | (unsigned)(~oi);
      }
    }
    __syncthreads();
  }
}

// K4: full bitonic sort of each 4096-half (fuses old k_sortA + k_merge4096).
// 64 blocks: b = blk>>1, half m = blk&1. Half m sorted desc iff m==0.
__global__ __launch_bounds__(512) void k_sortB(u64* __restrict__ cand,
                                               const unsigned* __restrict__ cnt) {
  __shared__ u64 sm[4096];   // 32 KiB
  int blk = blockIdx.x;
  int b = blk >> 1, m = blk & 1;
  unsigned effcnt = cnt[b * 64];
  if (effcnt > CAND_CAP) effcnt = CAND_CAP;
  u64* cb = cand + (size_t)b * CAND_CAP + (size_t)m * 4096;
  int base = m * 4096;
  int tid = threadIdx.x;
  for (int t = tid; t < 4096; t += 512)
    sm[t] = ((unsigned)(base + t) < effcnt) ? cb[t] : 0ull;
  bool blkdesc = (m == 0);
  for (int k = 2; k <= 4096; k <<= 1) {
    for (int j = k >> 1; j > 0; j >>= 1) {
      __syncthreads();
      for (int t = tid; t < 4096; t += 512) {
        int p = t ^ j;
        if (p > t) {
          bool up = (k == 4096) ? blkdesc : ((t & k) == 0);
          u64 x = sm[t], y = sm[p];
          if (up ? (x < y) : (x > y)) { sm[t] = y; sm[p] = x; }
        }
      }
    }
  }
  __syncthreads();
  for (int t = tid; t < 4096; t += 512) cb[t] = sm[t];
}

// K5: FUSED final merge (k=8192 desc) + parallel decode + compacted greedy NMS.
// The 8192-key merge runs in the same LDS bytes that later hold the 6144
// decoded boxes (keys staged to registers before the overwrite).
__global__ __launch_bounds__(1024) void k_final2(const u64* __restrict__ cand,
    const float* __restrict__ dl, const float* __restrict__ info,
    float* __restrict__ out) {
  __shared__ float4 bx[NBOX];        // 96 KiB; aliased as u64 sm[8192] during merge
  __shared__ float4 cbox2[CH];       // compacted alive boxes (score order)
  __shared__ float  carea2[CH];
  __shared__ float4 kbox[POST_N];
  __shared__ float  karea[POST_N];
  __shared__ unsigned supf[CH];
  __shared__ u64 sup[CH][9];         // 36 KiB, padded row to break bank stride
  __shared__ u64 aliveM[8];
  __shared__ u64 kgW[8];
  __shared__ int s_nk;
  u64* sm = (u64*)bx;

  int b = blockIdx.x, tid = threadIdx.x;
  int lane = tid & 63;
  if (tid == 0) s_nk = 0;

  // ---- load + final 13-phase bitonic merge (desc) of 8192 keys in LDS ----
  const u64* cb = cand + (size_t)b * CAND_CAP;
  for (int t = tid; t < CAND_CAP; t += 1024) sm[t] = cb[t];
  for (int j = CAND_CAP >> 1; j > 0; j >>= 1) {
    __syncthreads();
    for (int t = tid; t < CAND_CAP; t += 1024) {
      int p = t ^ j;
      if (p > t) {
        u64 x = sm[t], y = sm[p];
        if (x < y) { sm[t] = y; sm[p] = x; }
      }
    }
  }
  __syncthreads();

  // ---- stage top-6144 keys to registers, then decode in parallel into bx ----
  u64 kreg[6];
  #pragma unroll
  for (int k = 0; k < 6; ++k) {
    int t = tid + k * 1024;
    kreg[k] = (t < PRE_N) ? sm[t] : 0ull;
  }
  __syncthreads();   // all key reads done before bx overwrites the same bytes

  const float* dlb = dl + (size_t)b * (4*NA*HW);
  float imh = info[b*3+0], imw = info[b*3+1];
  #pragma unroll
  for (int k = 0; k < 6; ++k) {
    int t = tid + k * 1024;
    u64 ck = kreg[k];
    float4 v = make_float4(0.f, 0.f, -1.f, -1.f);   // invalid: width 0
    if ((unsigned)(ck >> 32) != 0u) {
      int idx = (int)(~(unsigned)(ck & 0xFFFFFFFFull));
      int a = idx % 9, hw = idx / 9;
      v = decode_clip(a, hw >> 7, hw & 127,
                      dlb[(a*4+0)*HW + hw], dlb[(a*4+1)*HW + hw],
                      dlb[(a*4+2)*HW + hw], dlb[(a*4+3)*HW + hw], imh, imw);
    }
    bx[t] = v;
  }
  __syncthreads();

  // ---- greedy NMS over 12 chunks of 512, compacted per chunk ----
  float* ob = out + (size_t)b * (POST_N * 5);
  int c = tid & (CH - 1);
  int seg = tid >> 9;                      // 0/1 split

  for (int base = 0; base < NBOX; base += CH) {
    if (tid < CH) {
      float4 v = bx[base + tid];
      supf[tid] = (v.z - v.x + 1.0f > 0.0f) ? 0u : 1u;
    }
    __syncthreads();                                          // B1
    int nk0 = s_nk;

    // pre-filter vs kept list (2-way depth split, break on own hit only;
    // no cross-thread poll — that was a serial LDS load per iteration)
    if (supf[c] == 0u && nk0 > 0) {
      float4 v = bx[base + c];
      float ar = (v.z - v.x + 1.0f) * (v.w - v.y + 1.0f);
      bool dead = false;
      for (int k = seg; k < nk0; k += 2) {
        if (sup_test4(v, ar, kbox[k], karea[k])) { dead = true; break; }
      }
      if (dead) supf[c] = 1u;     // benign same-value race between segs
    }
    __syncthreads();                                          // B2

    if (tid < CH) {
      u64 am = __ballot(supf[tid] == 0u);
      if (lane == 0) aliveM[tid >> 6] = am;
    }
    __syncthreads();                                          // B3

    int na = 0;
    #pragma unroll
    for (int g = 0; g < 8; ++g) na += (int)__popcll(aliveM[g]);
    if (na == 0) continue;

    // compaction (order-preserving => still descending score order)
    if (tid < CH && supf[tid] == 0u) {
      int cg2 = tid >> 6;
      int pre = 0;
      #pragma unroll
      for (int g = 0; g < 8; ++g) if (g < cg2) pre += (int)__popcll(aliveM[g]);
      pre += (int)__popcll(aliveM[cg2] & ((1ull << (tid & 63)) - 1ull));
      float4 v = bx[base + tid];
      cbox2[pre] = v;
      carea2[pre] = (v.z - v.x + 1.0f) * (v.w - v.y + 1.0f);
    }
    __syncthreads();                                          // B4

    // dense suppression triangle on compacted set: row i tests vs all j<i.
    // Fixed-bound unrollable loops, broadcast reads (lanes in a wave share g,j).
    {
      int i = c;
      if (i < na) {
        int ngi = (i >> 6) + 1;
        int gA = seg ? (ngi >> 1) : 0;
        int gB = seg ? ngi : (ngi >> 1);
        if (gA < gB) {
          float4 vi = cbox2[i];
          float ai = carea2[i];
          for (int g = gA; g < gB; ++g) {
            int jmax = i - (g << 6);
            if (jmax > 64) jmax = 64;
            u64 r = 0;
            #pragma unroll 4
            for (int j = 0; j < jmax; ++j) {
              if (sup_test4(vi, ai, cbox2[(g << 6) + j], carea2[(g << 6) + j]))
                r |= 1ull << j;
            }
            sup[i][g] = r;
          }
        }
      }
    }
    __syncthreads();                                          // B5

    // greedy resolve by wave 0 over dense groups of 64
    if (tid < 64) {
      u64 kw[8];
      #pragma unroll
      for (int s = 0; s < 8; ++s) {
        u64 kg = 0;
        if (s * 64 < na) {
          int cc = s * 64 + lane;
          bool a = (cc < na);
          #pragma unroll
          for (int g = 0; g < 8; ++g) {
            if (g < s && a) a = (sup[cc][g] & kw[g]) == 0ull;
          }
          u64 r = a ? sup[cc][s] : 0ull;
          u64 cm = __ballot(a);
          while (cm) {
            int j = __builtin_ctzll(cm);
            kg |= 1ull << j;
            u64 rem = __ballot((r >> j) & 1ull);
            cm &= ~(rem | (1ull << j));
          }
        }
        kw[s] = kg;
      }
      if (lane == 0) {
        #pragma unroll
        for (int s = 0; s < 8; ++s) kgW[s] = kw[s];
      }
    }
    __syncthreads();                                          // B6

    // append kept boxes + update s_nk
    if (tid < na) {
      int s = tid >> 6;
      u64 kgw = kgW[s];
      bool kept = (kgw >> (tid & 63)) & 1;
      int pre = 0;
      #pragma unroll
      for (int g = 0; g < 8; ++g) if (g < s) pre += (int)__popcll(kgW[g]);
      pre += (int)__popcll(kgw & ((1ull << (tid & 63)) - 1ull));
      int rank = nk0 + pre;
      if (kept && rank < POST_N) {
        float4 v = cbox2[tid];
        kbox[rank] = v; karea[rank] = carea2[tid];
        ob[rank*5+0] = (float)b;
        ob[rank*5+1] = v.x; ob[rank*5+2] = v.y; ob[rank*5+3] = v.z; ob[rank*5+4] = v.w;
      }
    }
    if (tid == 0) {
      int tot = 0;
      #pragma unroll
      for (int s = 0; s < 8; ++s) tot += (int)__popcll(kgW[s]);
      int nn = nk0 + tot;
      s_nk = nn < POST_N ? nn : POST_N;
    }
    __syncthreads();                                          // B7
    if (s_nk >= POST_N) break;
  }
  __syncthreads();
  int nk = s_nk;
  for (int r = nk + tid; r < POST_N; r += 1024) {
    ob[r*5+0] = (float)b;
    ob[r*5+1] = 0.f; ob[r*5+2] = 0.f; ob[r*5+3] = 0.f; ob[r*5+4] = 0.f;
  }
}

extern "C" void kernel_launch(void* const* d_in, const int* in_sizes, int n_in,
                              void* d_out, int out_size, void* d_ws, size_t ws_size,
                              hipStream_t stream) {
  const float* cls  = (const float*)d_in[0];   // (32, 18, 128, 128)
  const float* dl   = (const float*)d_in[1];   // (32, 36, 128, 128)
  const float* info = (const float*)d_in[2];   // (32, 3)
  float* out = (float*)d_out;                  // (32, 300, 5)
  char* ws = (char*)d_ws;

  // workspace layout (bytes)
  const size_t OFF_KEYS = 0;                        // 32*147456*4 = 18,874,368
  const size_t OFF_H1   = 18874368;                 // 32*4096*4   =    524,288
  const size_t OFF_H2   = 19398656;                 // 32*4096*4   =    524,288
  const size_t OFF_CNT  = 19922944;                 // 32*64*4     =      8,192
  const size_t OFF_CAND = 19931136;                 // 32*8192*8   =  2,097,152
  const size_t WS_NEED  = 22028288;
  if (ws_size < WS_NEED) return;

  unsigned* keys  = (unsigned*)(ws + OFF_KEYS);
  unsigned* h1    = (unsigned*)(ws + OFF_H1);
  unsigned* h2    = (unsigned*)(ws + OFF_H2);
  unsigned* cnt   = (unsigned*)(ws + OFF_CNT);
  u64* cand = (u64*)(ws + OFF_CAND);

  // zero h1 + h2 + cnt only (cand masked by cnt in k_sortB)
  hipMemsetAsync(ws + OFF_H1, 0, OFF_CAND - OFF_H1, stream);

  dim3 g1(HW / 1024, NB);                 // (16, 32)
  k_keys<<<g1, 256, 0, stream>>>(cls, dl, info, keys, h1);
  dim3 gh(8, NB);
  k_hist2<<<gh, 256, 0, stream>>>(keys, h1, h2);
  dim3 gg(GX_GATHER, NB);
  k_gather<<<gg, 256, 0, stream>>>(keys, h1, h2, cnt, cand);
  k_sortB<<<NB * 2, 512, 0, stream>>>(cand, cnt);
  k_final2<<<NB, 1024, 0, stream>>>(cand, dl, info, out);
}

// Round 4
// 402.281 us; speedup vs baseline: 1.0341x; 1.0217x over previous
//
#include <hip/hip_runtime.h>
#include <cstdint>
#include <cstddef>

#pragma clang fp contract(off)

typedef unsigned long long u64;

#define NB 32
#define NA 9
#define NH 128
#define NW 128
#define HW (NH*NW)            // 16384
#define NANCH (NA*HW)         // 147456
#define PRE_N 6000
#define POST_N 300
#define CAND_CAP 8192
#define NMS_T 0.7f
#define GX_GATHER 24          // blocks per image in k_gather
#define NBOX 6144             // boxes carried into NMS (PRE_N rounded up to chunk)
#define CH 512                // NMS chunk size

// Base anchor widths/heights (generate_anchors(16,[.5,1,2],[8,16,32])).
// All anchor centers are at (w*16+8, h*16+8) exactly (fp32-exact integers).
__constant__ float c_wa[9] = {184.f,368.f,736.f,128.f,256.f,512.f,88.f,176.f,352.f};
__constant__ float c_ha[9] = {96.f,192.f,384.f,128.f,256.f,512.f,176.f,352.f,704.f};

__device__ __forceinline__ float4 decode_clip(int a, int h, int w,
    float dx, float dy, float dlw, float dlh, float imh, float imw) {
  float wa = c_wa[a], ha = c_ha[a];
  float cx = (float)w * 16.0f + 8.0f;
  float cy = (float)h * 16.0f + 8.0f;
  float pcx = dx * wa + cx;
  float pcy = dy * ha + cy;
  float pw = expf(dlw) * wa;
  float ph = expf(dlh) * ha;
  float x1 = pcx - 0.5f * pw;
  float y1 = pcy - 0.5f * ph;
  float x2 = pcx + 0.5f * pw;
  float y2 = pcy + 0.5f * ph;
  float4 r;
  r.x = fminf(fmaxf(x1, 0.0f), imw - 1.0f);
  r.y = fminf(fmaxf(y1, 0.0f), imh - 1.0f);
  r.z = fminf(fmaxf(x2, 0.0f), imw - 1.0f);
  r.w = fminf(fmaxf(y2, 0.0f), imh - 1.0f);
  return r;
}

__device__ __forceinline__ unsigned score_key(float sc, float bw, float bh, float msz) {
  unsigned bits = __float_as_uint(sc);
  unsigned key = (bits & 0x80000000u) ? ~bits : (bits | 0x80000000u);
  if (!(bw >= msz && bh >= msz)) key = 0u;   // filtered == score NEG_INF
  return key;
}

// earlier/picked box (p,pa) vs candidate (v,ar):
// reference iou = inter / max(pa + ar - inter, 1e-6)
__device__ __forceinline__ bool sup_test4(float4 v, float ar, float4 p, float pa) {
  float xx1 = fmaxf(p.x, v.x), yy1 = fmaxf(p.y, v.y);
  float xx2 = fminf(p.z, v.z), yy2 = fminf(p.w, v.w);
  float iw = fmaxf(xx2 - xx1 + 1.0f, 0.0f);
  float ih = fmaxf(yy2 - yy1 + 1.0f, 0.0f);
  float inter = iw * ih;
  float iou = inter / fmaxf(pa + ar - inter, 1e-6f);
  return iou > NMS_T;
}

// ---- inline radix-select helpers (256-thread blocks) -----------------------
__device__ void find_B(const unsigned* __restrict__ hb, unsigned* part,
                       unsigned* outB, unsigned* outCum) {
  int tid = threadIdx.x;
  unsigned s = 0;
  for (int i = 0; i < 16; ++i) s += hb[tid*16 + i];
  part[tid] = s;
  __syncthreads();
  for (int off = 1; off < 256; off <<= 1) {
    unsigned v = (tid + off < 256) ? part[tid + off] : 0u;
    __syncthreads();
    part[tid] += v;
    __syncthreads();
  }
  unsigned St = part[tid];
  unsigned Sn = (tid < 255) ? part[tid + 1] : 0u;
  if (St >= (unsigned)PRE_N && Sn < (unsigned)PRE_N) {
    unsigned cum = Sn, B = 0, cumAbove = Sn;
    for (int i = 15; i >= 0; --i) {
      unsigned v = hb[tid*16 + i];
      if (cum + v >= (unsigned)PRE_N) { B = (unsigned)(tid*16 + i); cumAbove = cum; break; }
      cum += v;
    }
    *outB = B; *outCum = cumAbove;
  }
  __syncthreads();
}

__device__ void find_thr(const unsigned* __restrict__ hb2, unsigned B, unsigned cum0,
                         unsigned* part, unsigned* outThr) {
  int tid = threadIdx.x;
  unsigned s = 0;
  for (int i = 0; i < 16; ++i) s += hb2[tid*16 + i];
  part[tid] = s;
  __syncthreads();
  for (int off = 1; off < 256; off <<= 1) {
    unsigned v = (tid + off < 256) ? part[tid + off] : 0u;
    __syncthreads();
    part[tid] += v;
    __syncthreads();
  }
  unsigned St = cum0 + part[tid];
  unsigned Sn = cum0 + ((tid < 255) ? part[tid + 1] : 0u);
  if (St >= (unsigned)PRE_N && Sn < (unsigned)PRE_N) {
    unsigned cum = Sn, t = 1u;
    for (int i = 15; i >= 0; --i) {
      unsigned v = hb2[tid*16 + i];
      if (cum + v >= (unsigned)PRE_N) {
        t = (B << 20) | ((unsigned)(tid*16 + i) << 8);
        break;
      }
      cum += v;
    }
    if (t == 0u) t = 1u;
    *outThr = t;
  }
  __syncthreads();
}

// K1: decode+filter -> order-preserving uint key per anchor, fused coarse
// histogram (key>>20, 4096 bins) aggregated in LDS, flushed per block.
// grid (16, NB): 9216 keys per block -> one dense flush per block.
__global__ __launch_bounds__(256) void k_keys(const float* __restrict__ cls,
    const float* __restrict__ dl, const float* __restrict__ info,
    unsigned* __restrict__ keys, unsigned* __restrict__ hist) {
  __shared__ unsigned hsh[4096];
  int tid = threadIdx.x;
  for (int i = tid; i < 4096; i += 256) hsh[i] = 0;
  int t = blockIdx.x * 256 + tid;            // 0..4095
  int b = blockIdx.y;
  int hw0 = t * 4;                           // 4 consecutive hw, same row
  int h = hw0 >> 7;
  const float* dlb  = dl  + (size_t)b * (4*NA*HW);
  const float* clsb = cls + (size_t)b * (2*NA*HW);
  float imh = info[b*3+0], imw = info[b*3+1];
  float msz = 16.0f * info[b*3+2];
  unsigned* kb = keys + (size_t)b * NANCH;
  __syncthreads();
  #pragma unroll
  for (int a = 0; a < 9; ++a) {
    float4 dx4 = *(const float4*)&dlb[(a*4+0)*HW + hw0];
    float4 dy4 = *(const float4*)&dlb[(a*4+1)*HW + hw0];
    float4 dw4 = *(const float4*)&dlb[(a*4+2)*HW + hw0];
    float4 dh4 = *(const float4*)&dlb[(a*4+3)*HW + hw0];
    float4 sc4 = *(const float4*)&clsb[(NA+a)*HW + hw0];
    uint4 out;
    {
      float4 bx = decode_clip(a, h, (hw0+0)&127, dx4.x, dy4.x, dw4.x, dh4.x, imh, imw);
      out.x = score_key(sc4.x, bx.z-bx.x+1.0f, bx.w-bx.y+1.0f, msz);
    }
    {
      float4 bx = decode_clip(a, h, (hw0+1)&127, dx4.y, dy4.y, dw4.y, dh4.y, imh, imw);
      out.y = score_key(sc4.y, bx.z-bx.x+1.0f, bx.w-bx.y+1.0f, msz);
    }
    {
      float4 bx = decode_clip(a, h, (hw0+2)&127, dx4.z, dy4.z, dw4.z, dh4.z, imh, imw);
      out.z = score_key(sc4.z, bx.z-bx.x+1.0f, bx.w-bx.y+1.0f, msz);
    }
    {
      float4 bx = decode_clip(a, h, (hw0+3)&127, dx4.w, dy4.w, dw4.w, dh4.w, imh, imw);
      out.w = score_key(sc4.w, bx.z-bx.x+1.0f, bx.w-bx.y+1.0f, msz);
    }
    *(uint4*)&kb[a*HW + hw0] = out;
    atomicAdd(&hsh[out.x >> 20], 1u);
    atomicAdd(&hsh[out.y >> 20], 1u);
    atomicAdd(&hsh[out.z >> 20], 1u);
    atomicAdd(&hsh[out.w >> 20], 1u);
  }
  __syncthreads();
  unsigned* gb = hist + ((size_t)b << 12);
  for (int i = tid; i < 4096; i += 256) {
    unsigned v = hsh[i];
    if (v) atomicAdd(&gb[i], v);
  }
}

// K2: refine histogram — bits[19:8] of keys whose top-12 == B (B inline from h1).
__global__ __launch_bounds__(256) void k_hist2(const unsigned* __restrict__ keys,
    const unsigned* __restrict__ hist1, unsigned* __restrict__ hist2) {
  __shared__ unsigned h[4096];
  __shared__ unsigned part[256];
  __shared__ unsigned sB, sCum;
  int b = blockIdx.y, tid = threadIdx.x;
  for (int i = tid; i < 4096; i += 256) h[i] = 0;
  __syncthreads();
  find_B(hist1 + ((size_t)b << 12), part, &sB, &sCum);
  unsigned B = sB;
  const unsigned* kb = keys + (size_t)b * NANCH;
  for (int i = blockIdx.x * 256 + tid; i < NANCH; i += gridDim.x * 256) {
    unsigned k = kb[i];
    if ((k >> 20) == B) atomicAdd(&h[(k >> 8) & 4095u], 1u);
  }
  __syncthreads();
  unsigned* gb = hist2 + ((size_t)b << 12);
  for (int i = tid; i < 4096; i += 256) { unsigned v = h[i]; if (v) atomicAdd(&gb[i], v); }
}

// K3: gather (key, [~oi:18|pos:13]) for key >= thr, AND decode the box into
// boxes[b][pos] (float4). Payload keeps exact reference tie-break (~oi in the
// high bits of the low word); pos lets the final kernel fetch the box without
// touching dl at all.
__global__ __launch_bounds__(256) void k_gather(const unsigned* __restrict__ keys,
    const unsigned* __restrict__ hist1, const unsigned* __restrict__ hist2,
    const float* __restrict__ dl, const float* __restrict__ info,
    unsigned* __restrict__ cnt, u64* __restrict__ cand,
    float4* __restrict__ boxes) {
  int b = blockIdx.y, tid = threadIdx.x;
  int lane = tid & 63, wv = tid >> 6;
  __shared__ unsigned part[256];
  __shared__ unsigned sB, sCum, sThr;
  __shared__ unsigned wcnt[4], woff[4], blkbase;
  if (tid == 0) sThr = 1u;
  __syncthreads();
  find_B(hist1 + ((size_t)b << 12), part, &sB, &sCum);
  find_thr(hist2 + ((size_t)b << 12), sB, sCum, part, &sThr);
  unsigned t_ = sThr;
  const unsigned* kb = keys + (size_t)b * NANCH;
  const float* dlb = dl + (size_t)b * (4*NA*HW);
  float imh = info[b*3+0], imw = info[b*3+1];
  u64* cb = cand + (size_t)b * CAND_CAP;
  float4* bxc = boxes + (size_t)b * CAND_CAP;
  unsigned* cp = cnt + (size_t)b * 64;
  const int PER_BLK = NANCH / GX_GATHER;      // 6144
  int base0 = blockIdx.x * PER_BLK;
  for (int it = 0; it < PER_BLK / 256; ++it) {
    int j = base0 + it * 256 + tid;
    unsigned key = kb[j];
    bool pass = key >= t_;
    u64 mask = __ballot(pass);
    if (lane == 0) wcnt[wv] = (unsigned)__popcll(mask);
    __syncthreads();
    if (tid == 0) {
      unsigned s0 = 0;
      for (int w = 0; w < 4; ++w) { woff[w] = s0; s0 += wcnt[w]; }
      blkbase = s0 ? atomicAdd(cp, s0) : 0u;
    }
    __syncthreads();
    if (pass) {
      unsigned pos = blkbase + woff[wv] + (unsigned)__popcll(mask & ((1ull << lane) - 1ull));
      if (pos < CAND_CAP) {
        int a = j >> 14, hw = j & (HW - 1);
        unsigned oi = (unsigned)(hw * 9 + a);
        unsigned noi = (~oi) & 0x3FFFFu;          // 18-bit inverted index
        cb[pos] = ((u64)key << 32) | ((u64)noi << 13) | (u64)pos;
        bxc[pos] = decode_clip(a, hw >> 7, hw & 127,
                               dlb[(a*4+0)*HW + hw], dlb[(a*4+1)*HW + hw],
                               dlb[(a*4+2)*HW + hw], dlb[(a*4+3)*HW + hw],
                               imh, imw);
      }
    }
    __syncthreads();
  }
}

// K4: FUSED full 8192 bitonic sort (desc, 91 phases in LDS) + box gather
// (from the boxes array — no dl/exp work here) + compacted greedy NMS.
// The sort runs in the same LDS bytes that later hold the 6144 boxes
// (keys staged to registers before the overwrite).
__global__ __launch_bounds__(1024) void k_final3(const u64* __restrict__ cand,
    const unsigned* __restrict__ cnt, const float4* __restrict__ boxes,
    float* __restrict__ out) {
  __shared__ float4 bx[NBOX];        // 96 KiB; aliased as u64 sm[8192] during sort
  __shared__ float4 cbox2[CH];       // compacted alive boxes (score order)
  __shared__ float  carea2[CH];
  __shared__ float4 kbox[POST_N];
  __shared__ float  karea[POST_N];
  __shared__ unsigned supf[CH];
  __shared__ u64 sup[CH][9];         // 36 KiB, padded row to break bank stride
  __shared__ u64 aliveM[8];
  __shared__ u64 kgW[8];
  __shared__ int s_nk;
  u64* sm = (u64*)bx;

  int b = blockIdx.x, tid = threadIdx.x;
  int lane = tid & 63;
  if (tid == 0) s_nk = 0;

  // ---- load (masked by cnt) + full bitonic sort desc of 8192 keys in LDS ----
  unsigned effcnt = cnt[b * 64];
  if (effcnt > CAND_CAP) effcnt = CAND_CAP;
  const u64* cb = cand + (size_t)b * CAND_CAP;
  for (int t = tid; t < CAND_CAP; t += 1024)
    sm[t] = ((unsigned)t < effcnt) ? cb[t] : 0ull;
  for (int k = 2; k <= CAND_CAP; k <<= 1) {
    for (int j = k >> 1; j > 0; j >>= 1) {
      __syncthreads();
      for (int t = tid; t < CAND_CAP; t += 1024) {
        int p = t ^ j;
        if (p > t) {
          bool up = (t & k) == 0;          // up-region = descending
          u64 x = sm[t], y = sm[p];
          if (up ? (x < y) : (x > y)) { sm[t] = y; sm[p] = x; }
        }
      }
    }
  }
  __syncthreads();

  // ---- stage top-6144 keys to registers, then fetch boxes into bx ----
  u64 kreg[6];
  #pragma unroll
  for (int k = 0; k < 6; ++k) {
    int t = tid + k * 1024;
    kreg[k] = (t < PRE_N) ? sm[t] : 0ull;
  }
  __syncthreads();   // all key reads done before bx overwrites the same bytes

  const float4* bxc = boxes + (size_t)b * CAND_CAP;
  #pragma unroll
  for (int k = 0; k < 6; ++k) {
    int t = tid + k * 1024;
    u64 ck = kreg[k];
    float4 v = make_float4(0.f, 0.f, -1.f, -1.f);   // invalid: width 0
    if ((unsigned)(ck >> 32) != 0u)
      v = bxc[(unsigned)(ck & 0x1FFFu)];
    bx[t] = v;
  }
  __syncthreads();

  // ---- greedy NMS over 12 chunks of 512, compacted per chunk ----
  float* ob = out + (size_t)b * (POST_N * 5);
  int c = tid & (CH - 1);
  int seg = tid >> 9;                      // 0/1 split

  for (int base = 0; base < NBOX; base += CH) {
    if (tid < CH) {
      float4 v = bx[base + tid];
      supf[tid] = (v.z - v.x + 1.0f > 0.0f) ? 0u : 1u;
    }
    __syncthreads();                                          // B1
    int nk0 = s_nk;

    // pre-filter vs kept list (2-way depth split, break on own hit only)
    if (supf[c] == 0u && nk0 > 0) {
      float4 v = bx[base + c];
      float ar = (v.z - v.x + 1.0f) * (v.w - v.y + 1.0f);
      bool dead = false;
      for (int k = seg; k < nk0; k += 2) {
        if (sup_test4(v, ar, kbox[k], karea[k])) { dead = true; break; }
      }
      if (dead) supf[c] = 1u;     // benign same-value race between segs
    }
    __syncthreads();                                          // B2

    if (tid < CH) {
      u64 am = __ballot(supf[tid] == 0u);
      if (lane == 0) aliveM[tid >> 6] = am;
    }
    __syncthreads();                                          // B3

    int na = 0;
    #pragma unroll
    for (int g = 0; g < 8; ++g) na += (int)__popcll(aliveM[g]);
    if (na == 0) continue;

    // compaction (order-preserving => still descending score order)
    if (tid < CH && supf[tid] == 0u) {
      int cg2 = tid >> 6;
      int pre = 0;
      #pragma unroll
      for (int g = 0; g < 8; ++g) if (g < cg2) pre += (int)__popcll(aliveM[g]);
      pre += (int)__popcll(aliveM[cg2] & ((1ull << (tid & 63)) - 1ull));
      float4 v = bx[base + tid];
      cbox2[pre] = v;
      carea2[pre] = (v.z - v.x + 1.0f) * (v.w - v.y + 1.0f);
    }
    __syncthreads();                                          // B4

    // dense suppression triangle on compacted set: row i tests vs all j<i.
    {
      int i = c;
      if (i < na) {
        int ngi = (i >> 6) + 1;
        int gA = seg ? (ngi >> 1) : 0;
        int gB = seg ? ngi : (ngi >> 1);
        if (gA < gB) {
          float4 vi = cbox2[i];
          float ai = carea2[i];
          for (int g = gA; g < gB; ++g) {
            int jmax = i - (g << 6);
            if (jmax > 64) jmax = 64;
            u64 r = 0;
            #pragma unroll 4
            for (int j = 0; j < jmax; ++j) {
              if (sup_test4(vi, ai, cbox2[(g << 6) + j], carea2[(g << 6) + j]))
                r |= 1ull << j;
            }
            sup[i][g] = r;
          }
        }
      }
    }
    __syncthreads();                                          // B5

    // greedy resolve by wave 0 over dense groups of 64
    if (tid < 64) {
      u64 kw[8];
      #pragma unroll
      for (int s = 0; s < 8; ++s) {
        u64 kg = 0;
        if (s * 64 < na) {
          int cc = s * 64 + lane;
          bool a = (cc < na);
          #pragma unroll
          for (int g = 0; g < 8; ++g) {
            if (g < s && a) a = (sup[cc][g] & kw[g]) == 0ull;
          }
          u64 r = a ? sup[cc][s] : 0ull;
          u64 cm = __ballot(a);
          while (cm) {
            int j = __builtin_ctzll(cm);
            kg |= 1ull << j;
            u64 rem = __ballot((r >> j) & 1ull);
            cm &= ~(rem | (1ull << j));
          }
        }
        kw[s] = kg;
      }
      if (lane == 0) {
        #pragma unroll
        for (int s = 0; s < 8; ++s) kgW[s] = kw[s];
      }
    }
    __syncthreads();                                          // B6

    // append kept boxes + update s_nk
    if (tid < na) {
      int s = tid >> 6;
      u64 kgw = kgW[s];
      bool kept = (kgw >> (tid & 63)) & 1;
      int pre = 0;
      #pragma unroll
      for (int g = 0; g < 8; ++g) if (g < s) pre += (int)__popcll(kgW[g]);
      pre += (int)__popcll(kgw & ((1ull << (tid & 63)) - 1ull));
      int rank = nk0 + pre;
      if (kept && rank < POST_N) {
        float4 v = cbox2[tid];
        kbox[rank] = v; karea[rank] = carea2[tid];
        ob[rank*5+0] = (float)b;
        ob[rank*5+1] = v.x; ob[rank*5+2] = v.y; ob[rank*5+3] = v.z; ob[rank*5+4] = v.w;
      }
    }
    if (tid == 0) {
      int tot = 0;
      #pragma unroll
      for (int s = 0; s < 8; ++s) tot += (int)__popcll(kgW[s]);
      int nn = nk0 + tot;
      s_nk = nn < POST_N ? nn : POST_N;
    }
    __syncthreads();                                          // B7
    if (s_nk >= POST_N) break;
  }
  __syncthreads();
  int nk = s_nk;
  for (int r = nk + tid; r < POST_N; r += 1024) {
    ob[r*5+0] = (float)b;
    ob[r*5+1] = 0.f; ob[r*5+2] = 0.f; ob[r*5+3] = 0.f; ob[r*5+4] = 0.f;
  }
}

extern "C" void kernel_launch(void* const* d_in, const int* in_sizes, int n_in,
                              void* d_out, int out_size, void* d_ws, size_t ws_size,
                              hipStream_t stream) {
  const float* cls  = (const float*)d_in[0];   // (32, 18, 128, 128)
  const float* dl   = (const float*)d_in[1];   // (32, 36, 128, 128)
  const float* info = (const float*)d_in[2];   // (32, 3)
  float* out = (float*)d_out;                  // (32, 300, 5)
  char* ws = (char*)d_ws;

  // workspace layout (bytes)
  const size_t OFF_KEYS = 0;                        // 32*147456*4 = 18,874,368
  const size_t OFF_H1   = 18874368;                 // 32*4096*4   =    524,288
  const size_t OFF_H2   = 19398656;                 // 32*4096*4   =    524,288
  const size_t OFF_CNT  = 19922944;                 // 32*64*4     =      8,192
  const size_t OFF_CAND = 19931136;                 // 32*8192*8   =  2,097,152
  const size_t OFF_BOX  = 22028288;                 // 32*8192*16  =  4,194,304
  const size_t WS_NEED  = 26222592;
  if (ws_size < WS_NEED) return;

  unsigned* keys  = (unsigned*)(ws + OFF_KEYS);
  unsigned* h1    = (unsigned*)(ws + OFF_H1);
  unsigned* h2    = (unsigned*)(ws + OFF_H2);
  unsigned* cnt   = (unsigned*)(ws + OFF_CNT);
  u64* cand = (u64*)(ws + OFF_CAND);
  float4* boxes = (float4*)(ws + OFF_BOX);

  // zero h1 + h2 + cnt only (cand masked by cnt in k_final3)
  hipMemsetAsync(ws + OFF_H1, 0, OFF_CAND - OFF_H1, stream);

  dim3 g1(HW / 1024, NB);                 // (16, 32)
  k_keys<<<g1, 256, 0, stream>>>(cls, dl, info, keys, h1);
  dim3 gh(8, NB);
  k_hist2<<<gh, 256, 0, stream>>>(keys, h1, h2);
  dim3 gg(GX_GATHER, NB);
  k_gather<<<gg, 256, 0, stream>>>(keys, h1, h2, dl, info, cnt, cand, boxes);
  k_final3<<<NB, 1024, 0, stream>>>(cand, cnt, boxes, out);
}

// Round 5
// 332.427 us; speedup vs baseline: 1.2514x; 1.2101x over previous
//
#include <hip/hip_runtime.h>
#include <cstdint>
#include <cstddef>

#pragma clang fp contract(off)

typedef unsigned long long u64;

#define NB 32
#define NA 9
#define NH 128
#define NW 128
#define HW (NH*NW)            // 16384
#define NANCH (NA*HW)         // 147456
#define PRE_N 6000
#define POST_N 300
#define CAND_CAP 8192
#define NMS_T 0.7f
#define GX_GATHER 24          // blocks per image in k_gather
#define NBOX 6144             // boxes carried into NMS (PRE_N rounded up to chunk)
#define CH 512                // NMS chunk size

// Base anchor widths/heights (generate_anchors(16,[.5,1,2],[8,16,32])).
__constant__ float c_wa[9] = {184.f,368.f,736.f,128.f,256.f,512.f,88.f,176.f,352.f};
__constant__ float c_ha[9] = {96.f,192.f,384.f,128.f,256.f,512.f,176.f,352.f,704.f};

__device__ __forceinline__ float4 decode_clip(int a, int h, int w,
    float dx, float dy, float dlw, float dlh, float imh, float imw) {
  float wa = c_wa[a], ha = c_ha[a];
  float cx = (float)w * 16.0f + 8.0f;
  float cy = (float)h * 16.0f + 8.0f;
  float pcx = dx * wa + cx;
  float pcy = dy * ha + cy;
  float pw = expf(dlw) * wa;
  float ph = expf(dlh) * ha;
  float x1 = pcx - 0.5f * pw;
  float y1 = pcy - 0.5f * ph;
  float x2 = pcx + 0.5f * pw;
  float y2 = pcy + 0.5f * ph;
  float4 r;
  r.x = fminf(fmaxf(x1, 0.0f), imw - 1.0f);
  r.y = fminf(fmaxf(y1, 0.0f), imh - 1.0f);
  r.z = fminf(fmaxf(x2, 0.0f), imw - 1.0f);
  r.w = fminf(fmaxf(y2, 0.0f), imh - 1.0f);
  return r;
}

__device__ __forceinline__ unsigned score_key(float sc, float bw, float bh, float msz) {
  unsigned bits = __float_as_uint(sc);
  unsigned key = (bits & 0x80000000u) ? ~bits : (bits | 0x80000000u);
  if (!(bw >= msz && bh >= msz)) key = 0u;   // filtered == score NEG_INF
  return key;
}

__device__ __forceinline__ bool sup_test4(float4 v, float ar, float4 p, float pa) {
  float xx1 = fmaxf(p.x, v.x), yy1 = fmaxf(p.y, v.y);
  float xx2 = fminf(p.z, v.z), yy2 = fminf(p.w, v.w);
  float iw = fmaxf(xx2 - xx1 + 1.0f, 0.0f);
  float ih = fmaxf(yy2 - yy1 + 1.0f, 0.0f);
  float inter = iw * ih;
  float iou = inter / fmaxf(pa + ar - inter, 1e-6f);
  return iou > NMS_T;
}

// ---- hybrid bitonic sort helpers (1024 threads, 8 elems/thread) ------------
__device__ __forceinline__ u64 shfl_xor_u64(u64 x, int m) {
  int lo = __shfl_xor((int)(unsigned)x, m, 64);
  int hi = __shfl_xor((int)(unsigned)(x >> 32), m, 64);
  return ((u64)(unsigned)hi << 32) | (unsigned)lo;
}

// j < 8: partner within thread
__device__ __forceinline__ void reg_step(u64 v[8], int t, int k, int j) {
  #pragma unroll
  for (int r = 0; r < 8; ++r) {
    if ((r & j) == 0) {
      int e = (t << 3) + r;
      bool up = ((e & k) == 0);          // up-region = descending
      u64 x = v[r], y = v[r | j];
      u64 mx = x > y ? x : y, mn = x > y ? y : x;
      v[r]     = up ? mx : mn;
      v[r | j] = up ? mn : mx;
    }
  }
}

// 8 <= j <= 256: partner lane t^(j>>3), same wave, no barrier
__device__ __forceinline__ void shfl_step(u64 v[8], int t, int k, int j) {
  int m = j >> 3;
  bool lower = ((t & m) == 0);
  #pragma unroll
  for (int r = 0; r < 8; ++r) {
    int e = (t << 3) + r;
    bool up = ((e & k) == 0);
    u64 pv = shfl_xor_u64(v[r], m);
    bool keepmax = (up == lower);
    u64 x = v[r];
    u64 mx = x > pv ? x : pv, mn = x > pv ? pv : x;
    v[r] = keepmax ? mx : mn;
  }
}

// j >= 512: cross-wave exchange via LDS. Swizzled layout slot(e) =
// (e&7)*1024 + (e>>3): lane-stride = 8B on both write and read (2-way bank
// alias = free) instead of 64B stride (32-way conflict).
__device__ __forceinline__ void lds_step(u64* sm, u64 v[8], int t, int k, int j) {
  int m = j >> 3;                        // >= 64: different wave
  __syncthreads();                       // protect previous step's reads
  #pragma unroll
  for (int r = 0; r < 8; ++r) sm[(r << 10) | t] = v[r];
  __syncthreads();
  bool lower = ((t & m) == 0);
  bool up = (((t << 3) & k) == 0);       // k >= 1024: r-bits irrelevant
  bool keepmax = (up == lower);
  int pt = t ^ m;
  #pragma unroll
  for (int r = 0; r < 8; ++r) {
    u64 pv = sm[(r << 10) | pt];
    u64 x = v[r];
    u64 mx = x > pv ? x : pv, mn = x > pv ? pv : x;
    v[r] = keepmax ? mx : mn;
  }
}

// ---- inline radix-select helpers (256-thread blocks) -----------------------
__device__ void find_B(const unsigned* __restrict__ hb, unsigned* part,
                       unsigned* outB, unsigned* outCum) {
  int tid = threadIdx.x;
  unsigned s = 0;
  for (int i = 0; i < 16; ++i) s += hb[tid*16 + i];
  part[tid] = s;
  __syncthreads();
  for (int off = 1; off < 256; off <<= 1) {
    unsigned v = (tid + off < 256) ? part[tid + off] : 0u;
    __syncthreads();
    part[tid] += v;
    __syncthreads();
  }
  unsigned St = part[tid];
  unsigned Sn = (tid < 255) ? part[tid + 1] : 0u;
  if (St >= (unsigned)PRE_N && Sn < (unsigned)PRE_N) {
    unsigned cum = Sn, B = 0, cumAbove = Sn;
    for (int i = 15; i >= 0; --i) {
      unsigned v = hb[tid*16 + i];
      if (cum + v >= (unsigned)PRE_N) { B = (unsigned)(tid*16 + i); cumAbove = cum; break; }
      cum += v;
    }
    *outB = B; *outCum = cumAbove;
  }
  __syncthreads();
}

__device__ void find_thr(const unsigned* __restrict__ hb2, unsigned B, unsigned cum0,
                         unsigned* part, unsigned* outThr) {
  int tid = threadIdx.x;
  unsigned s = 0;
  for (int i = 0; i < 16; ++i) s += hb2[tid*16 + i];
  part[tid] = s;
  __syncthreads();
  for (int off = 1; off < 256; off <<= 1) {
    unsigned v = (tid + off < 256) ? part[tid + off] : 0u;
    __syncthreads();
    part[tid] += v;
    __syncthreads();
  }
  unsigned St = cum0 + part[tid];
  unsigned Sn = cum0 + ((tid < 255) ? part[tid + 1] : 0u);
  if (St >= (unsigned)PRE_N && Sn < (unsigned)PRE_N) {
    unsigned cum = Sn, t = 1u;
    for (int i = 15; i >= 0; --i) {
      unsigned v = hb2[tid*16 + i];
      if (cum + v >= (unsigned)PRE_N) {
        t = (B << 20) | ((unsigned)(tid*16 + i) << 8);
        break;
      }
      cum += v;
    }
    if (t == 0u) t = 1u;
    *outThr = t;
  }
  __syncthreads();
}

// K1: decode+filter -> order-preserving uint key per anchor, fused coarse
// histogram (key>>20, 4096 bins) aggregated in LDS, flushed per block.
__global__ __launch_bounds__(256) void k_keys(const float* __restrict__ cls,
    const float* __restrict__ dl, const float* __restrict__ info,
    unsigned* __restrict__ keys, unsigned* __restrict__ hist) {
  __shared__ unsigned hsh[4096];
  int tid = threadIdx.x;
  for (int i = tid; i < 4096; i += 256) hsh[i] = 0;
  int t = blockIdx.x * 256 + tid;            // 0..4095
  int b = blockIdx.y;
  int hw0 = t * 4;                           // 4 consecutive hw, same row
  int h = hw0 >> 7;
  const float* dlb  = dl  + (size_t)b * (4*NA*HW);
  const float* clsb = cls + (size_t)b * (2*NA*HW);
  float imh = info[b*3+0], imw = info[b*3+1];
  float msz = 16.0f * info[b*3+2];
  unsigned* kb = keys + (size_t)b * NANCH;
  __syncthreads();
  #pragma unroll
  for (int a = 0; a < 9; ++a) {
    float4 dx4 = *(const float4*)&dlb[(a*4+0)*HW + hw0];
    float4 dy4 = *(const float4*)&dlb[(a*4+1)*HW + hw0];
    float4 dw4 = *(const float4*)&dlb[(a*4+2)*HW + hw0];
    float4 dh4 = *(const float4*)&dlb[(a*4+3)*HW + hw0];
    float4 sc4 = *(const float4*)&clsb[(NA+a)*HW + hw0];
    uint4 out;
    {
      float4 bx = decode_clip(a, h, (hw0+0)&127, dx4.x, dy4.x, dw4.x, dh4.x, imh, imw);
      out.x = score_key(sc4.x, bx.z-bx.x+1.0f, bx.w-bx.y+1.0f, msz);
    }
    {
      float4 bx = decode_clip(a, h, (hw0+1)&127, dx4.y, dy4.y, dw4.y, dh4.y, imh, imw);
      out.y = score_key(sc4.y, bx.z-bx.x+1.0f, bx.w-bx.y+1.0f, msz);
    }
    {
      float4 bx = decode_clip(a, h, (hw0+2)&127, dx4.z, dy4.z, dw4.z, dh4.z, imh, imw);
      out.z = score_key(sc4.z, bx.z-bx.x+1.0f, bx.w-bx.y+1.0f, msz);
    }
    {
      float4 bx = decode_clip(a, h, (hw0+3)&127, dx4.w, dy4.w, dw4.w, dh4.w, imh, imw);
      out.w = score_key(sc4.w, bx.z-bx.x+1.0f, bx.w-bx.y+1.0f, msz);
    }
    *(uint4*)&kb[a*HW + hw0] = out;
    atomicAdd(&hsh[out.x >> 20], 1u);
    atomicAdd(&hsh[out.y >> 20], 1u);
    atomicAdd(&hsh[out.z >> 20], 1u);
    atomicAdd(&hsh[out.w >> 20], 1u);
  }
  __syncthreads();
  unsigned* gb = hist + ((size_t)b << 12);
  for (int i = tid; i < 4096; i += 256) {
    unsigned v = hsh[i];
    if (v) atomicAdd(&gb[i], v);
  }
}

// K2: refine histogram — bits[19:8] of keys whose top-12 == B (B inline from h1).
__global__ __launch_bounds__(256) void k_hist2(const unsigned* __restrict__ keys,
    const unsigned* __restrict__ hist1, unsigned* __restrict__ hist2) {
  __shared__ unsigned h[4096];
  __shared__ unsigned part[256];
  __shared__ unsigned sB, sCum;
  int b = blockIdx.y, tid = threadIdx.x;
  for (int i = tid; i < 4096; i += 256) h[i] = 0;
  __syncthreads();
  find_B(hist1 + ((size_t)b << 12), part, &sB, &sCum);
  unsigned B = sB;
  const unsigned* kb = keys + (size_t)b * NANCH;
  for (int i = blockIdx.x * 256 + tid; i < NANCH; i += gridDim.x * 256) {
    unsigned k = kb[i];
    if ((k >> 20) == B) atomicAdd(&h[(k >> 8) & 4095u], 1u);
  }
  __syncthreads();
  unsigned* gb = hist2 + ((size_t)b << 12);
  for (int i = tid; i < 4096; i += 256) { unsigned v = h[i]; if (v) atomicAdd(&gb[i], v); }
}

// K3: gather (key, [~oi:18|pos:13]) for key >= thr, AND decode the box into
// boxes[b][pos]. Tie-break preserved (~oi); pos lets the final kernel fetch
// the box without touching dl.
__global__ __launch_bounds__(256) void k_gather(const unsigned* __restrict__ keys,
    const unsigned* __restrict__ hist1, const unsigned* __restrict__ hist2,
    const float* __restrict__ dl, const float* __restrict__ info,
    unsigned* __restrict__ cnt, u64* __restrict__ cand,
    float4* __restrict__ boxes) {
  int b = blockIdx.y, tid = threadIdx.x;
  int lane = tid & 63, wv = tid >> 6;
  __shared__ unsigned part[256];
  __shared__ unsigned sB, sCum, sThr;
  __shared__ unsigned wcnt[4], woff[4], blkbase;
  if (tid == 0) sThr = 1u;
  __syncthreads();
  find_B(hist1 + ((size_t)b << 12), part, &sB, &sCum);
  find_thr(hist2 + ((size_t)b << 12), sB, sCum, part, &sThr);
  unsigned t_ = sThr;
  const unsigned* kb = keys + (size_t)b * NANCH;
  const float* dlb = dl + (size_t)b * (4*NA*HW);
  float imh = info[b*3+0], imw = info[b*3+1];
  u64* cb = cand + (size_t)b * CAND_CAP;
  float4* bxc = boxes + (size_t)b * CAND_CAP;
  unsigned* cp = cnt + (size_t)b * 64;
  const int PER_BLK = NANCH / GX_GATHER;      // 6144
  int base0 = blockIdx.x * PER_BLK;
  for (int it = 0; it < PER_BLK / 256; ++it) {
    int j = base0 + it * 256 + tid;
    unsigned key = kb[j];
    bool pass = key >= t_;
    u64 mask = __ballot(pass);
    if (lane == 0) wcnt[wv] = (unsigned)__popcll(mask);
    __syncthreads();
    if (tid == 0) {
      unsigned s0 = 0;
      for (int w = 0; w < 4; ++w) { woff[w] = s0; s0 += wcnt[w]; }
      blkbase = s0 ? atomicAdd(cp, s0) : 0u;
    }
    __syncthreads();
    if (pass) {
      unsigned pos = blkbase + woff[wv] + (unsigned)__popcll(mask & ((1ull << lane) - 1ull));
      if (pos < CAND_CAP) {
        int a = j >> 14, hw = j & (HW - 1);
        unsigned oi = (unsigned)(hw * 9 + a);
        unsigned noi = (~oi) & 0x3FFFFu;          // 18-bit inverted index
        cb[pos] = ((u64)key << 32) | ((u64)noi << 13) | (u64)pos;
        bxc[pos] = decode_clip(a, hw >> 7, hw & 127,
                               dlb[(a*4+0)*HW + hw], dlb[(a*4+1)*HW + hw],
                               dlb[(a*4+2)*HW + hw], dlb[(a*4+3)*HW + hw],
                               imh, imw);
      }
    }
    __syncthreads();
  }
}

// K4: hybrid-bitonic full sort (8 elems/thread in regs; j<8 register, j=8..256
// wave shuffle, j>=512 LDS — only 10 barriered steps of 91) + box gather +
// compacted greedy NMS. Sort LDS aliases the box array.
__global__ __launch_bounds__(1024) void k_final4(const u64* __restrict__ cand,
    const unsigned* __restrict__ cnt, const float4* __restrict__ boxes,
    float* __restrict__ out) {
  __shared__ float4 bx[NBOX];        // 96 KiB; first 64 KiB aliased as u64 sm[8192]
  __shared__ float4 cbox2[CH];       // compacted alive boxes (score order)
  __shared__ float  carea2[CH];
  __shared__ float4 kbox[POST_N];
  __shared__ float  karea[POST_N];
  __shared__ unsigned supf[CH];
  __shared__ u64 sup[CH][9];         // padded row to break bank stride
  __shared__ u64 aliveM[8];
  __shared__ u64 kgW[8];
  __shared__ int s_nk;
  u64* sm = (u64*)bx;

  int b = blockIdx.x, tid = threadIdx.x;
  int lane = tid & 63;
  if (tid == 0) s_nk = 0;

  // ---- load 8 consecutive candidates into registers (masked by cnt) ----
  unsigned effcnt = cnt[b * 64];
  if (effcnt > CAND_CAP) effcnt = CAND_CAP;
  const u64* cb = cand + (size_t)b * CAND_CAP;
  int e0 = tid << 3;
  u64 v[8];
  #pragma unroll
  for (int r = 0; r < 8; ++r)
    v[r] = ((unsigned)(e0 + r) < effcnt) ? cb[e0 + r] : 0ull;

  // ---- full bitonic sort, descending ----
  for (int k = 2; k <= 8; k <<= 1)
    for (int j = k >> 1; j >= 1; j >>= 1) reg_step(v, tid, k, j);
  for (int k = 16; k <= CAND_CAP; k <<= 1) {
    int j = k >> 1;
    for (; j >= 512; j >>= 1) lds_step(sm, v, tid, k, j);
    for (; j >= 8;   j >>= 1) shfl_step(v, tid, k, j);
    for (; j >= 1;   j >>= 1) reg_step(v, tid, k, j);
  }
  __syncthreads();   // all lds_step reads done before bx overwrites sm bytes

  // ---- fill bx by rank from the boxes array (ranks >= PRE_N masked) ----
  const float4* bxc = boxes + (size_t)b * CAND_CAP;
  #pragma unroll
  for (int r = 0; r < 8; ++r) {
    int rank = e0 + r;
    if (rank < NBOX) {
      u64 ck = (rank < PRE_N) ? v[r] : 0ull;
      float4 w = make_float4(0.f, 0.f, -1.f, -1.f);   // invalid: width 0
      if ((unsigned)(ck >> 32) != 0u)
        w = bxc[(unsigned)(ck & 0x1FFFu)];
      bx[rank] = w;
    }
  }
  __syncthreads();

  // ---- greedy NMS over 12 chunks of 512, compacted per chunk ----
  float* ob = out + (size_t)b * (POST_N * 5);
  int c = tid & (CH - 1);
  int seg = tid >> 9;                      // 0/1 split

  for (int base = 0; base < NBOX; base += CH) {
    if (tid < CH) {
      float4 w = bx[base + tid];
      supf[tid] = (w.z - w.x + 1.0f > 0.0f) ? 0u : 1u;
    }
    __syncthreads();                                          // B1
    int nk0 = s_nk;

    // pre-filter vs kept list (2-way depth split, break on own hit only)
    if (supf[c] == 0u && nk0 > 0) {
      float4 w = bx[base + c];
      float ar = (w.z - w.x + 1.0f) * (w.w - w.y + 1.0f);
      bool dead = false;
      for (int k = seg; k < nk0; k += 2) {
        if (sup_test4(w, ar, kbox[k], karea[k])) { dead = true; break; }
      }
      if (dead) supf[c] = 1u;     // benign same-value race between segs
    }
    __syncthreads();                                          // B2

    if (tid < CH) {
      u64 am = __ballot(supf[tid] == 0u);
      if (lane == 0) aliveM[tid >> 6] = am;
    }
    __syncthreads();                                          // B3

    int na = 0;
    #pragma unroll
    for (int g = 0; g < 8; ++g) na += (int)__popcll(aliveM[g]);
    if (na == 0) continue;

    // compaction (order-preserving => still descending score order)
    if (tid < CH && supf[tid] == 0u) {
      int cg2 = tid >> 6;
      int pre = 0;
      #pragma unroll
      for (int g = 0; g < 8; ++g) if (g < cg2) pre += (int)__popcll(aliveM[g]);
      pre += (int)__popcll(aliveM[cg2] & ((1ull << (tid & 63)) - 1ull));
      float4 w = bx[base + tid];
      cbox2[pre] = w;
      carea2[pre] = (w.z - w.x + 1.0f) * (w.w - w.y + 1.0f);
    }
    __syncthreads();                                          // B4

    // dense suppression triangle on compacted set: row i tests vs all j<i
    {
      int i = c;
      if (i < na) {
        int ngi = (i >> 6) + 1;
        int gA = seg ? (ngi >> 1) : 0;
        int gB = seg ? ngi : (ngi >> 1);
        if (gA < gB) {
          float4 vi = cbox2[i];
          float ai = carea2[i];
          for (int g = gA; g < gB; ++g) {
            int jmax = i - (g << 6);
            if (jmax > 64) jmax = 64;
            u64 r = 0;
            #pragma unroll 4
            for (int j = 0; j < jmax; ++j) {
              if (sup_test4(vi, ai, cbox2[(g << 6) + j], carea2[(g << 6) + j]))
                r |= 1ull << j;
            }
            sup[i][g] = r;
          }
        }
      }
    }
    __syncthreads();                                          // B5

    // greedy resolve by wave 0 over dense groups of 64
    if (tid < 64) {
      u64 kw[8];
      #pragma unroll
      for (int s = 0; s < 8; ++s) {
        u64 kg = 0;
        if (s * 64 < na) {
          int cc = s * 64 + lane;
          bool a = (cc < na);
          #pragma unroll
          for (int g = 0; g < 8; ++g) {
            if (g < s && a) a = (sup[cc][g] & kw[g]) == 0ull;
          }
          u64 r = a ? sup[cc][s] : 0ull;
          u64 cm = __ballot(a);
          while (cm) {
            int j = __builtin_ctzll(cm);
            kg |= 1ull << j;
            u64 rem = __ballot((r >> j) & 1ull);
            cm &= ~(rem | (1ull << j));
          }
        }
        kw[s] = kg;
      }
      if (lane == 0) {
        #pragma unroll
        for (int s = 0; s < 8; ++s) kgW[s] = kw[s];
      }
    }
    __syncthreads();                                          // B6

    // append kept boxes + update s_nk
    if (tid < na) {
      int s = tid >> 6;
      u64 kgw = kgW[s];
      bool kept = (kgw >> (tid & 63)) & 1;
      int pre = 0;
      #pragma unroll
      for (int g = 0; g < 8; ++g) if (g < s) pre += (int)__popcll(kgW[g]);
      pre += (int)__popcll(kgw & ((1ull << (tid & 63)) - 1ull));
      int rank = nk0 + pre;
      if (kept && rank < POST_N) {
        float4 w = cbox2[tid];
        kbox[rank] = w; karea[rank] = carea2[tid];
        ob[rank*5+0] = (float)b;
        ob[rank*5+1] = w.x; ob[rank*5+2] = w.y; ob[rank*5+3] = w.z; ob[rank*5+4] = w.w;
      }
    }
    if (tid == 0) {
      int tot = 0;
      #pragma unroll
      for (int s = 0; s < 8; ++s) tot += (int)__popcll(kgW[s]);
      int nn = nk0 + tot;
      s_nk = nn < POST_N ? nn : POST_N;
    }
    __syncthreads();                                          // B7
    if (s_nk >= POST_N) break;
  }
  __syncthreads();
  int nk = s_nk;
  for (int r = nk + tid; r < POST_N; r += 1024) {
    ob[r*5+0] = (float)b;
    ob[r*5+1] = 0.f; ob[r*5+2] = 0.f; ob[r*5+3] = 0.f; ob[r*5+4] = 0.f;
  }
}

extern "C" void kernel_launch(void* const* d_in, const int* in_sizes, int n_in,
                              void* d_out, int out_size, void* d_ws, size_t ws_size,
                              hipStream_t stream) {
  const float* cls  = (const float*)d_in[0];   // (32, 18, 128, 128)
  const float* dl   = (const float*)d_in[1];   // (32, 36, 128, 128)
  const float* info = (const float*)d_in[2];   // (32, 3)
  float* out = (float*)d_out;                  // (32, 300, 5)
  char* ws = (char*)d_ws;

  // workspace layout (bytes)
  const size_t OFF_KEYS = 0;                        // 32*147456*4 = 18,874,368
  const size_t OFF_H1   = 18874368;                 // 32*4096*4   =    524,288
  const size_t OFF_H2   = 19398656;                 // 32*4096*4   =    524,288
  const size_t OFF_CNT  = 19922944;                 // 32*64*4     =      8,192
  const size_t OFF_CAND = 19931136;                 // 32*8192*8   =  2,097,152
  const size_t OFF_BOX  = 22028288;                 // 32*8192*16  =  4,194,304
  const size_t WS_NEED  = 26222592;
  if (ws_size < WS_NEED) return;

  unsigned* keys  = (unsigned*)(ws + OFF_KEYS);
  unsigned* h1    = (unsigned*)(ws + OFF_H1);
  unsigned* h2    = (unsigned*)(ws + OFF_H2);
  unsigned* cnt   = (unsigned*)(ws + OFF_CNT);
  u64* cand = (u64*)(ws + OFF_CAND);
  float4* boxes = (float4*)(ws + OFF_BOX);

  // zero h1 + h2 + cnt only (cand masked by cnt in k_final4)
  hipMemsetAsync(ws + OFF_H1, 0, OFF_CAND - OFF_H1, stream);

  dim3 g1(HW / 1024, NB);                 // (16, 32)
  k_keys<<<g1, 256, 0, stream>>>(cls, dl, info, keys, h1);
  dim3 gh(8, NB);
  k_hist2<<<gh, 256, 0, stream>>>(keys, h1, h2);
  dim3 gg(GX_GATHER, NB);
  k_gather<<<gg, 256, 0, stream>>>(keys, h1, h2, dl, info, cnt, cand, boxes);
  k_final4<<<NB, 1024, 0, stream>>>(cand, cnt, boxes, out);
}